// Round 1
// baseline (197.377 us; speedup 1.0000x reference)
//
#include <hip/hip_runtime.h>

#define N_E   512
#define DIM   64
#define HW    4096        // 64*64
#define CHW   (64*HW)     // 262144
#define NPIX  131072      // 32*64*64
#define CHUNK 128         // codes per LDS chunk

// --- kernel 1: per-code squared norms -> d_ws ---------------------------------
__global__ void vq_cnorm(const float* __restrict__ cb, float* __restrict__ cnorm) {
    int j = blockIdx.x * blockDim.x + threadIdx.x;
    if (j < N_E) {
        const float4* c = (const float4*)(cb + j * DIM);
        float s = 0.f;
        #pragma unroll
        for (int k = 0; k < DIM / 4; ++k) {
            float4 v = c[k];
            s += v.x * v.x + v.y * v.y + v.z * v.z + v.w * v.w;
        }
        cnorm[j] = s;
    }
}

// --- kernel 2: main VQ: argmin + q write + block partial loss -----------------
__global__ __launch_bounds__(256) void vq_main(
        const float* __restrict__ z, const float* __restrict__ cb,
        const float* __restrict__ cnorm, float* __restrict__ out,
        float* __restrict__ partials) {
    __shared__ float cb_lds[CHUNK * DIM];   // 32 KB
    __shared__ float cn[N_E];               // 2 KB
    __shared__ float red[4];

    const int tid = threadIdx.x;
    const int p0  = blockIdx.x * 512 + tid;   // pixel A; pixel B = p0 + 256
    const int b   = p0 >> 12;                 // p0 / 4096
    const int hw  = p0 & 4095;

    for (int i = tid; i < N_E; i += 256) cn[i] = cnorm[i];

    // gather both pixels' 64 channels (stride HW; coalesced across lanes)
    const float* zp0 = z + (size_t)b * CHW + hw;
    float za[DIM], zb[DIM];
    #pragma unroll
    for (int k = 0; k < DIM; ++k) {
        za[k] = zp0[k * HW];
        zb[k] = zp0[k * HW + 256];
    }

    float bestA = 1e30f, bestB = 1e30f;
    int ia = 0, ib = 0;

    for (int c = 0; c < N_E / CHUNK; ++c) {
        __syncthreads();
        const float4* src = (const float4*)(cb + c * CHUNK * DIM);
        float4* dst = (float4*)cb_lds;
        #pragma unroll
        for (int i = 0; i < (CHUNK * DIM / 4) / 256; ++i)
            dst[tid + i * 256] = src[tid + i * 256];
        __syncthreads();

        #pragma unroll 2
        for (int j = 0; j < CHUNK; ++j) {
            const float4* cv = (const float4*)(cb_lds + j * DIM);
            float d0 = 0.f, d1 = 0.f, e0 = 0.f, e1 = 0.f;  // 4 indep chains
            #pragma unroll
            for (int k4 = 0; k4 < DIM / 4; ++k4) {
                float4 c4 = cv[k4];
                d0 = fmaf(za[4*k4+0], c4.x, d0);
                e0 = fmaf(zb[4*k4+0], c4.x, e0);
                d1 = fmaf(za[4*k4+1], c4.y, d1);
                e1 = fmaf(zb[4*k4+1], c4.y, e1);
                d0 = fmaf(za[4*k4+2], c4.z, d0);
                e0 = fmaf(zb[4*k4+2], c4.z, e0);
                d1 = fmaf(za[4*k4+3], c4.w, d1);
                e1 = fmaf(zb[4*k4+3], c4.w, e1);
            }
            const int   jj  = c * CHUNK + j;
            const float cnj = cn[jj];
            const float sA  = cnj - 2.f * (d0 + d1);
            const float sB  = cnj - 2.f * (e0 + e1);
            if (sA < bestA) { bestA = sA; ia = jj; }   // strict < => first index (matches argmin)
            if (sB < bestB) { bestB = sB; ib = jj; }
        }
    }

    // epilogue: write q (B,C,H,W layout) and accumulate ||z - q||^2 exactly
    float s = 0.f;
    const float4* qa = (const float4*)(cb + ia * DIM);
    const float4* qb = (const float4*)(cb + ib * DIM);
    float* o = out + 1 + (size_t)b * CHW + hw;
    #pragma unroll
    for (int k4 = 0; k4 < DIM / 4; ++k4) {
        float4 a4 = qa[k4], b4 = qb[k4];
        o[(4*k4+0) * HW]       = a4.x;
        o[(4*k4+1) * HW]       = a4.y;
        o[(4*k4+2) * HW]       = a4.z;
        o[(4*k4+3) * HW]       = a4.w;
        o[(4*k4+0) * HW + 256] = b4.x;
        o[(4*k4+1) * HW + 256] = b4.y;
        o[(4*k4+2) * HW + 256] = b4.z;
        o[(4*k4+3) * HW + 256] = b4.w;
        float dv;
        dv = za[4*k4+0] - a4.x; s = fmaf(dv, dv, s);
        dv = za[4*k4+1] - a4.y; s = fmaf(dv, dv, s);
        dv = za[4*k4+2] - a4.z; s = fmaf(dv, dv, s);
        dv = za[4*k4+3] - a4.w; s = fmaf(dv, dv, s);
        dv = zb[4*k4+0] - b4.x; s = fmaf(dv, dv, s);
        dv = zb[4*k4+1] - b4.y; s = fmaf(dv, dv, s);
        dv = zb[4*k4+2] - b4.z; s = fmaf(dv, dv, s);
        dv = zb[4*k4+3] - b4.w; s = fmaf(dv, dv, s);
    }

    #pragma unroll
    for (int off = 32; off; off >>= 1) s += __shfl_down(s, off);
    if ((tid & 63) == 0) red[tid >> 6] = s;
    __syncthreads();
    if (tid == 0) partials[blockIdx.x] = red[0] + red[1] + red[2] + red[3];
}

// --- kernel 3: final loss reduction ------------------------------------------
__global__ void vq_reduce(const float* __restrict__ partials, float* __restrict__ out) {
    __shared__ float red[4];
    int t = threadIdx.x;   // 256 threads, 256 partials
    float s = partials[t];
    #pragma unroll
    for (int off = 32; off; off >>= 1) s += __shfl_down(s, off);
    if ((t & 63) == 0) red[t >> 6] = s;
    __syncthreads();
    if (t == 0)
        out[0] = 1.25f * (red[0] + red[1] + red[2] + red[3]) / (float)(NPIX * DIM);
}

extern "C" void kernel_launch(void* const* d_in, const int* in_sizes, int n_in,
                              void* d_out, int out_size, void* d_ws, size_t ws_size,
                              hipStream_t stream) {
    const float* z  = (const float*)d_in[0];   // 32*64*64*64 f32, (B,C,H,W)
    const float* cb = (const float*)d_in[1];   // 512*64 f32
    float* out = (float*)d_out;                // [loss(1) | zq(8388608)]
    float* ws  = (float*)d_ws;
    float* partials = ws;                      // 256 floats
    float* cnorm    = ws + 256;                // 512 floats

    vq_cnorm<<<2, 256, 0, stream>>>(cb, cnorm);
    vq_main<<<256, 256, 0, stream>>>(z, cb, cnorm, out, partials);
    vq_reduce<<<1, 256, 0, stream>>>(partials, out);
}

// Round 2
// 38.478 us; speedup vs baseline: 5.1296x; 5.1296x over previous
//
#include <hip/hip_runtime.h>

#define N_E   512
#define DIM   64
#define HW    4096        // 64*64
#define CHW   (64*HW)     // 262144
#define NPIX  131072      // 32*64*64

typedef __attribute__((ext_vector_type(8))) short  short8;   // 8 bf16 (4 VGPRs)
typedef __attribute__((ext_vector_type(4))) float  f32x4;

__device__ __forceinline__ unsigned short f2bf(float x) {
    unsigned u = __builtin_bit_cast(unsigned, x);
    unsigned r = (u + 0x7FFFu + ((u >> 16) & 1u)) >> 16;   // RNE
    return (unsigned short)r;
}

// --- prep 1: cnh[j] = -0.5 * ||c_j||^2 (fp32) --------------------------------
__global__ void vq_prep_norms(const float* __restrict__ cb, float* __restrict__ cnh) {
    int j = blockIdx.x * 256 + threadIdx.x;
    if (j < N_E) {
        const float4* c = (const float4*)(cb + j * DIM);
        float s = 0.f;
        #pragma unroll
        for (int k = 0; k < DIM / 4; ++k) {
            float4 v = c[k];
            s += v.x * v.x + v.y * v.y + v.z * v.z + v.w * v.w;
        }
        cnh[j] = -0.5f * s;
    }
}

// --- prep 2: codebook -> bf16 B-fragment order -------------------------------
// frag[g], g = tile*128 + h*64 + lane : 8 bf16 = cb[tile*16 + (lane&15)][h*32 + (lane>>4)*8 + j]
__global__ void vq_prep_frag(const float* __restrict__ cb, uint4* __restrict__ frag) {
    int g    = blockIdx.x * 512 + threadIdx.x;   // 0..4095
    int tile = g >> 7;
    int h    = (g >> 6) & 1;
    int lane = g & 63;
    const float* src = cb + (tile * 16 + (lane & 15)) * DIM + h * 32 + (lane >> 4) * 8;
    float4 a = *(const float4*)src;
    float4 b = *(const float4*)(src + 4);
    uint4 o;
    o.x = (unsigned)f2bf(a.x) | ((unsigned)f2bf(a.y) << 16);
    o.y = (unsigned)f2bf(a.z) | ((unsigned)f2bf(a.w) << 16);
    o.z = (unsigned)f2bf(b.x) | ((unsigned)f2bf(b.y) << 16);
    o.w = (unsigned)f2bf(b.z) | ((unsigned)f2bf(b.w) << 16);
    frag[g] = o;
}

// --- main: MFMA scores + argmin + fp32 epilogue ------------------------------
__global__ __launch_bounds__(512, 4) void vq_main(
        const float* __restrict__ z, const float* __restrict__ cb,
        const float* __restrict__ cnh, const uint4* __restrict__ frag,
        float* __restrict__ out, float* __restrict__ partials) {
    __shared__ uint4 Blds[4096];     // 64 KB, B-fragment order (lane-linear reads)
    __shared__ float cn[N_E];        // 2 KB
    __shared__ int   idx_lds[256];   // per-pixel chosen code
    __shared__ float red[8];

    const int tid  = threadIdx.x;
    const int w    = tid >> 6;
    const int lane = tid & 63;
    const int col  = lane & 15;
    const int grp  = lane >> 4;

    #pragma unroll
    for (int i = 0; i < 8; ++i) Blds[tid + i * 512] = frag[tid + i * 512];
    if (tid < N_E) cn[tid] = cnh[tid];
    __syncthreads();

    const int pbase = blockIdx.x * 256;        // 256 pixels/block, same b
    const int b     = pbase >> 12;
    const int hwp   = (pbase & 4095) + w * 32 + col;
    const float* zp = z + (size_t)b * CHW + hwp;   // + m*16 + k*HW

    // load z fp32 (kept for exact loss) + build bf16 A-fragments
    float  zf[2][2][8];
    short8 afr[2][2];
    #pragma unroll
    for (int m = 0; m < 2; ++m)
        #pragma unroll
        for (int h = 0; h < 2; ++h)
            #pragma unroll
            for (int j = 0; j < 8; ++j) {
                float v = zp[m * 16 + (h * 32 + grp * 8 + j) * HW];
                zf[m][h][j] = v;
                afr[m][h][j] = (short)f2bf(v);
            }

    float best[2][4];
    int   bid[2][4];
    #pragma unroll
    for (int m = 0; m < 2; ++m)
        #pragma unroll
        for (int r = 0; r < 4; ++r) { best[m][r] = -1e30f; bid[m][r] = 0; }

    const short8* B8 = (const short8*)Blds;
    #pragma unroll 2
    for (int t = 0; t < 32; ++t) {
        const float c0 = cn[t * 16 + col];          // -0.5*||c||^2, per code col
        f32x4 a0 = {c0, c0, c0, c0};
        f32x4 a1 = {c0, c0, c0, c0};
        short8 b0 = B8[t * 128 + lane];
        short8 b1 = B8[t * 128 + 64 + lane];
        a0 = __builtin_amdgcn_mfma_f32_16x16x32_bf16(afr[0][0], b0, a0, 0, 0, 0);
        a0 = __builtin_amdgcn_mfma_f32_16x16x32_bf16(afr[0][1], b1, a0, 0, 0, 0);
        a1 = __builtin_amdgcn_mfma_f32_16x16x32_bf16(afr[1][0], b0, a1, 0, 0, 0);
        a1 = __builtin_amdgcn_mfma_f32_16x16x32_bf16(afr[1][1], b1, a1, 0, 0, 0);
        #pragma unroll
        for (int r = 0; r < 4; ++r) {
            if (a0[r] > best[0][r]) { best[0][r] = a0[r]; bid[0][r] = t; }
            if (a1[r] > best[1][r]) { best[1][r] = a1[r]; bid[1][r] = t; }
        }
    }

    // cross-lane argmax over the 16 cols of each group; tie -> smaller code
    #pragma unroll
    for (int m = 0; m < 2; ++m)
        #pragma unroll
        for (int r = 0; r < 4; ++r) {
            float s = best[m][r];
            int   c = bid[m][r] * 16 + col;
            #pragma unroll
            for (int mk = 1; mk < 16; mk <<= 1) {
                float os = __shfl_xor(s, mk);
                int   oc = __shfl_xor(c, mk);
                if (os > s || (os == s && oc < c)) { s = os; c = oc; }
            }
            if (col == 0) idx_lds[w * 32 + m * 16 + grp * 4 + r] = c;
        }
    __syncthreads();

    // epilogue: write q (fp32, from codebook) + exact fp32 loss
    float ls = 0.f;
    float* ob = out + 1 + (size_t)b * CHW + hwp;
    #pragma unroll
    for (int m = 0; m < 2; ++m) {
        const int qi = idx_lds[w * 32 + m * 16 + col];
        const float* qp = cb + qi * DIM + grp * 8;
        #pragma unroll
        for (int h = 0; h < 2; ++h) {
            float4 qa = *(const float4*)(qp + h * 32);
            float4 qb = *(const float4*)(qp + h * 32 + 4);
            float q[8] = {qa.x, qa.y, qa.z, qa.w, qb.x, qb.y, qb.z, qb.w};
            #pragma unroll
            for (int j = 0; j < 8; ++j) {
                float d = zf[m][h][j] - q[j];
                ls = fmaf(d, d, ls);
                ob[m * 16 + (h * 32 + grp * 8 + j) * HW] = q[j];
            }
        }
    }

    #pragma unroll
    for (int off = 32; off; off >>= 1) ls += __shfl_down(ls, off);
    if (lane == 0) red[w] = ls;
    __syncthreads();
    if (tid == 0) {
        float s = 0.f;
        #pragma unroll
        for (int i = 0; i < 8; ++i) s += red[i];
        partials[blockIdx.x] = s;
    }
}

// --- final loss reduction ----------------------------------------------------
__global__ void vq_reduce(const float* __restrict__ partials, float* __restrict__ out) {
    __shared__ float red[8];
    int t = threadIdx.x;          // 512 threads, 512 partials
    float s = partials[t];
    #pragma unroll
    for (int off = 32; off; off >>= 1) s += __shfl_down(s, off);
    if ((t & 63) == 0) red[t >> 6] = s;
    __syncthreads();
    if (t == 0) {
        float a = 0.f;
        #pragma unroll
        for (int i = 0; i < 8; ++i) a += red[i];
        out[0] = 1.25f * a / (float)(NPIX * DIM);
    }
}

extern "C" void kernel_launch(void* const* d_in, const int* in_sizes, int n_in,
                              void* d_out, int out_size, void* d_ws, size_t ws_size,
                              hipStream_t stream) {
    const float* z  = (const float*)d_in[0];   // (32,64,64,64) f32
    const float* cb = (const float*)d_in[1];   // (512,64) f32
    float* out = (float*)d_out;                // [loss | zq]
    float* ws  = (float*)d_ws;
    float* cnh      = ws;                      // 512 f32
    float* partials = ws + 512;                // 512 f32
    uint4* frag     = (uint4*)(ws + 1024);     // 64 KB bf16 fragments

    vq_prep_norms<<<2, 256, 0, stream>>>(cb, cnh);
    vq_prep_frag<<<8, 512, 0, stream>>>(cb, frag);
    vq_main<<<512, 512, 0, stream>>>(z, cb, cnh, frag, out, partials);
    vq_reduce<<<1, 512, 0, stream>>>(partials, out);
}